// Round 1
// baseline (752.762 us; speedup 1.0000x reference)
//
#include <hip/hip_runtime.h>
#include <stdint.h>

#define DEVINL __device__ __forceinline__

typedef __attribute__((ext_vector_type(8))) __bf16 bf16x8;
typedef __attribute__((ext_vector_type(4))) float f32x4;

static constexpr int HID  = 2048;
static constexpr int NQ   = 6144;   // 3*HID
static constexpr int SEQ  = 2048;
static constexpr int NB   = 4;
static constexpr int MTOT = NB * SEQ;  // 8192

// round-to-nearest-even f32 -> bf16
DEVINL unsigned short f2bf(float f) {
  union { float f; uint32_t u; } x; x.f = f;
  uint32_t r = x.u + 0x7fffu + ((x.u >> 16) & 1u);
  return (unsigned short)(r >> 16);
}

typedef const __attribute__((address_space(1))) void gvoid_t;
typedef __attribute__((address_space(3))) void svoid_t;

// async global->LDS, 16B per lane; LDS dest = wave-uniform base + lane*16
DEVINL void gload_lds16(const void* g, void* s) {
  __builtin_amdgcn_global_load_lds((gvoid_t*)(uintptr_t)g,
                                   (svoid_t*)(uint32_t)(uintptr_t)s,
                                   16, 0, 0);
}

// ---------------- conversion kernels ----------------

__global__ void k_cvt(const float* __restrict__ in, unsigned short* __restrict__ out, int n4) {
  int i = blockIdx.x * blockDim.x + threadIdx.x;
  if (i >= n4) return;
  float4 v = ((const float4*)in)[i];
  ushort4 o;
  o.x = f2bf(v.x); o.y = f2bf(v.y); o.z = f2bf(v.z); o.w = f2bf(v.w);
  ((ushort4*)out)[i] = o;
}

// out[c][r] = bf16(in[r][c]); in is R x C
__global__ void k_transpose_cvt(const float* __restrict__ in, unsigned short* __restrict__ out,
                                int R, int C) {
  __shared__ float tile[32][33];
  int c0 = blockIdx.x * 32, r0 = blockIdx.y * 32;
  int tx = threadIdx.x & 31, ty = threadIdx.x >> 5;  // 32 x 8
  #pragma unroll
  for (int i = 0; i < 32; i += 8)
    tile[ty + i][tx] = in[(size_t)(r0 + ty + i) * C + (c0 + tx)];
  __syncthreads();
  #pragma unroll
  for (int i = 0; i < 32; i += 8)
    out[(size_t)(c0 + ty + i) * R + (r0 + tx)] = f2bf(tile[tx][ty + i]);
}

// ---------------- GEMM: C[M][N] = A[M][K] * BT[N][K]^T ----------------
// 128x128 tile, BK=64, 4 waves (2x2), 16x16x32 bf16 MFMA, acc 4x4 per wave.

template <int OUT_BF16>
__global__ __launch_bounds__(256, 2) void k_gemm(const unsigned short* __restrict__ A,
                                                 const unsigned short* __restrict__ BT,
                                                 void* __restrict__ Cout,
                                                 int M, int N, int K) {
  __shared__ unsigned short As[128 * 64];
  __shared__ unsigned short Bs[128 * 64];
  const int tid = threadIdx.x;
  const int w = tid >> 6, l = tid & 63;
  const int lane16 = l & 15, lgrp = l >> 4;
  const int bn = blockIdx.x, bm = blockIdx.y;
  const int wr = w >> 1, wc = w & 1;
  const int srow = l >> 3;          // 0..7 within chunk
  const int sk = (l & 7) * 8;       // k-offset (elements)

  f32x4 acc[4][4] = {};

  for (int k0 = 0; k0 < K; k0 += 64) {
    #pragma unroll
    for (int i = 0; i < 4; ++i) {
      const int chunk = i * 4 + w;              // 0..15, wave-uniform
      const int row = chunk * 8 + srow;         // 0..127
      gload_lds16(A  + (size_t)(bm * 128 + row) * K + k0 + sk, As + chunk * 512);
      gload_lds16(BT + (size_t)(bn * 128 + row) * K + k0 + sk, Bs + chunk * 512);
    }
    __syncthreads();
    #pragma unroll
    for (int kk = 0; kk < 2; ++kk) {
      bf16x8 af[4], bfr[4];
      #pragma unroll
      for (int m = 0; m < 4; ++m)
        af[m] = *(const bf16x8*)(As + (wr * 64 + m * 16 + lane16) * 64 + kk * 32 + lgrp * 8);
      #pragma unroll
      for (int n = 0; n < 4; ++n)
        bfr[n] = *(const bf16x8*)(Bs + (wc * 64 + n * 16 + lane16) * 64 + kk * 32 + lgrp * 8);
      #pragma unroll
      for (int m = 0; m < 4; ++m)
        #pragma unroll
        for (int n = 0; n < 4; ++n)
          acc[m][n] = __builtin_amdgcn_mfma_f32_16x16x32_bf16(af[m], bfr[n], acc[m][n], 0, 0, 0);
    }
    __syncthreads();
  }

  const int row0 = bm * 128 + wr * 64;
  const int col0 = bn * 128 + wc * 64;
  #pragma unroll
  for (int m = 0; m < 4; ++m) {
    #pragma unroll
    for (int n = 0; n < 4; ++n) {
      const int col = col0 + n * 16 + lane16;
      #pragma unroll
      for (int r = 0; r < 4; ++r) {
        const int row = row0 + m * 16 + lgrp * 4 + r;
        if (OUT_BF16)
          ((unsigned short*)Cout)[(size_t)row * N + col] = f2bf(acc[m][n][r]);
        else
          ((float*)Cout)[(size_t)row * N + col] = acc[m][n][r];
      }
    }
  }
}

// ---------------- build V^T per head ----------------
// Vt[(head*128 + d)*2048 + t] = QKV[b*2048 + h*128 + (t>>4)][(t&15)*384 + 256 + d]
__global__ void k_build_vt(const unsigned short* __restrict__ QKV, unsigned short* __restrict__ Vt) {
  const int head = blockIdx.y;       // 0..63
  const int s_rel = blockIdx.x;      // 0..127
  const int b = head >> 4, h = head & 15;
  const int d = threadIdx.x;         // 0..127
  const unsigned short* src = QKV + (size_t)(b * SEQ + h * 128 + s_rel) * NQ + 256 + d;
  unsigned short vals[16];
  #pragma unroll
  for (int c1 = 0; c1 < 16; ++c1) vals[c1] = src[c1 * 384];
  unsigned short* dst = Vt + ((size_t)head * 128 + d) * SEQ + s_rel * 16;
  #pragma unroll
  for (int c1 = 0; c1 < 16; ++c1) dst[c1] = vals[c1];
}

// ---------------- flash attention ----------------
// grid: (qt 0..15, head 0..63), 256 threads (4 waves). Each wave: 32 q-rows.
__global__ __launch_bounds__(256, 2) void k_attn(const unsigned short* __restrict__ QKV,
                                                 const unsigned short* __restrict__ Vt,
                                                 unsigned short* __restrict__ ATT) {
  __shared__ unsigned short Ks[64 * 128];   // [kv][d]
  __shared__ unsigned short Vs[128 * 64];   // [d][kv]
  __shared__ unsigned short Ps[4 * 32 * 64];// per-wave [32][64]
  const int tid = threadIdx.x, w = tid >> 6, l = tid & 63;
  const int lane16 = l & 15, lgrp = l >> 4;
  const int qt = blockIdx.x, head = blockIdx.y;
  const int b = head >> 4, h = head & 15;
  const float scale = 0.08838834764831845f;  // 1/sqrt(128)
  const int base_row = b * SEQ + h * 128;

  // Q fragments in registers: rows w*32 + m*16 + lane16, d = kb*32 + lgrp*8 ..+8
  bf16x8 qf[2][4];
  #pragma unroll
  for (int m = 0; m < 2; ++m) {
    const int rl = w * 32 + m * 16 + lane16;   // 0..127 local q row
    const unsigned short* qrow =
        QKV + (size_t)(base_row + qt * 8 + (rl >> 4)) * NQ + (rl & 15) * 384;
    #pragma unroll
    for (int kb = 0; kb < 4; ++kb)
      qf[m][kb] = *(const bf16x8*)(qrow + kb * 32 + lgrp * 8);
  }

  f32x4 oacc[2][8] = {};
  float mrun[2][4], lrun[2][4];
  #pragma unroll
  for (int m = 0; m < 2; ++m)
    #pragma unroll
    for (int r = 0; r < 4; ++r) { mrun[m][r] = -1e30f; lrun[m][r] = 0.f; }

  for (int kv0 = 0; kv0 < SEQ; kv0 += 64) {
    // stage K tile [64][128]
    #pragma unroll
    for (int i = 0; i < 4; ++i) {
      const int chunk = i * 4 + w;
      const int r = chunk * 4 + lgrp;          // kv row 0..63
      const unsigned short* gk =
          QKV + (size_t)(base_row + (kv0 >> 4) + (r >> 4)) * NQ + (r & 15) * 384 + 128 + lane16 * 8;
      gload_lds16(gk, Ks + chunk * 512);
    }
    // stage V^T tile [128][64]
    #pragma unroll
    for (int i = 0; i < 4; ++i) {
      const int chunk = i * 4 + w;
      const int dr = chunk * 8 + (l >> 3);
      const unsigned short* gv = Vt + ((size_t)head * 128 + dr) * SEQ + kv0 + (l & 7) * 8;
      gload_lds16(gv, Vs + chunk * 512);
    }
    __syncthreads();

    // S = Q K^T   (2 m-frags x 4 n-frags of 16x16, contraction over d=128)
    f32x4 sacc[2][4] = {};
    #pragma unroll
    for (int kb = 0; kb < 4; ++kb) {
      bf16x8 kf[4];
      #pragma unroll
      for (int n = 0; n < 4; ++n)
        kf[n] = *(const bf16x8*)(Ks + (n * 16 + lane16) * 128 + kb * 32 + lgrp * 8);
      #pragma unroll
      for (int m = 0; m < 2; ++m)
        #pragma unroll
        for (int n = 0; n < 4; ++n)
          sacc[m][n] = __builtin_amdgcn_mfma_f32_16x16x32_bf16(qf[m][kb], kf[n], sacc[m][n], 0, 0, 0);
    }

    // online softmax; write P (bf16) to per-wave LDS
    unsigned short* Pw = Ps + w * 2048;
    #pragma unroll
    for (int m = 0; m < 2; ++m) {
      #pragma unroll
      for (int r = 0; r < 4; ++r) {
        float mx = fmaxf(fmaxf(sacc[m][0][r], sacc[m][1][r]),
                         fmaxf(sacc[m][2][r], sacc[m][3][r]));
        #pragma unroll
        for (int off = 1; off < 16; off <<= 1) mx = fmaxf(mx, __shfl_xor(mx, off));
        const float mnew = fmaxf(mrun[m][r], mx);
        const float corr = __expf((mrun[m][r] - mnew) * scale);
        const int prow = m * 16 + lgrp * 4 + r;
        float ls = 0.f;
        #pragma unroll
        for (int n = 0; n < 4; ++n) {
          float p = __expf((sacc[m][n][r] - mnew) * scale);
          ls += p;
          Pw[prow * 64 + n * 16 + lane16] = f2bf(p);
        }
        #pragma unroll
        for (int off = 1; off < 16; off <<= 1) ls += __shfl_xor(ls, off);
        lrun[m][r] = lrun[m][r] * corr + ls;
        mrun[m][r] = mnew;
        #pragma unroll
        for (int nd = 0; nd < 8; ++nd) oacc[m][nd][r] *= corr;
      }
    }
    __syncthreads();  // P visible / safety

    // O += P V  (contraction over kv=64)
    #pragma unroll
    for (int kb = 0; kb < 2; ++kb) {
      bf16x8 pf[2];
      #pragma unroll
      for (int m = 0; m < 2; ++m)
        pf[m] = *(const bf16x8*)(Pw + (m * 16 + lane16) * 64 + kb * 32 + lgrp * 8);
      #pragma unroll
      for (int nd = 0; nd < 8; ++nd) {
        bf16x8 vf = *(const bf16x8*)(Vs + (nd * 16 + lane16) * 64 + kb * 32 + lgrp * 8);
        #pragma unroll
        for (int m = 0; m < 2; ++m)
          oacc[m][nd] = __builtin_amdgcn_mfma_f32_16x16x32_bf16(pf[m], vf, oacc[m][nd], 0, 0, 0);
      }
    }
    __syncthreads();  // before re-staging K/Vs
  }

  // epilogue: O /= l, scatter to ATT[b*2048 + h*128 + (t>>4)][(t&15)*128 + d]
  #pragma unroll
  for (int m = 0; m < 2; ++m) {
    #pragma unroll
    for (int r = 0; r < 4; ++r) {
      const float inv = 1.0f / lrun[m][r];
      const int rl = w * 32 + m * 16 + lgrp * 4 + r;  // local q row
      unsigned short* orow =
          ATT + (size_t)(base_row + qt * 8 + (rl >> 4)) * HID + (rl & 15) * 128;
      #pragma unroll
      for (int nd = 0; nd < 8; ++nd)
        orow[nd * 16 + lane16] = f2bf(oacc[m][nd][r] * inv);
    }
  }
}

// ---------------- launcher ----------------

extern "C" void kernel_launch(void* const* d_in, const int* in_sizes, int n_in,
                              void* d_out, int out_size, void* d_ws, size_t ws_size,
                              hipStream_t stream) {
  const float* X    = (const float*)d_in[0];  // (4,2048,2048)
  const float* Wqkv = (const float*)d_in[1];  // (2048,6144)
  const float* Wo   = (const float*)d_in[2];  // (2048,2048)
  float* OUT = (float*)d_out;

  char* ws = (char*)d_ws;
  constexpr size_t SZ_QKV   = (size_t)MTOT * NQ * 2;    // 100663296
  constexpr size_t SZ_XBF   = (size_t)MTOT * HID * 2;   //  33554432
  constexpr size_t SZ_WQKVT = (size_t)NQ * HID * 2;     //  25165824
  constexpr size_t SZ_WOT   = (size_t)HID * HID * 2;    //   8388608
  constexpr size_t SZ_VT    = (size_t)64 * 128 * SEQ * 2; // 33554432
  unsigned short* QKV   = (unsigned short*)(ws);
  unsigned short* Xbf   = (unsigned short*)(ws + SZ_QKV);
  unsigned short* WqkvT = (unsigned short*)(ws + SZ_QKV + SZ_XBF);
  unsigned short* WoT   = (unsigned short*)(ws + SZ_QKV + SZ_XBF + SZ_WQKVT);
  unsigned short* Vt    = (unsigned short*)(ws + SZ_QKV + SZ_XBF + SZ_WQKVT + SZ_WOT);
  unsigned short* ATT   = (unsigned short*)(ws + SZ_QKV + SZ_XBF + SZ_WQKVT + SZ_WOT + SZ_VT);

  // 1) convert / transpose weights+activations to bf16
  k_cvt<<<(MTOT * HID / 4 + 255) / 256, 256, 0, stream>>>(X, Xbf, MTOT * HID / 4);
  k_transpose_cvt<<<dim3(NQ / 32, HID / 32), 256, 0, stream>>>(Wqkv, WqkvT, HID, NQ);
  k_transpose_cvt<<<dim3(HID / 32, HID / 32), 256, 0, stream>>>(Wo, WoT, HID, HID);
  // 2) QKV projection
  k_gemm<1><<<dim3(NQ / 128, MTOT / 128), 256, 0, stream>>>(Xbf, WqkvT, QKV, MTOT, NQ, HID);
  // 3) gather V^T per head
  k_build_vt<<<dim3(128, 64), 128, 0, stream>>>(QKV, Vt);
  // 4) flash attention
  k_attn<<<dim3(16, 64), 256, 0, stream>>>(QKV, Vt, ATT);
  // 5) output projection
  k_gemm<0><<<dim3(HID / 128, MTOT / 128), 256, 0, stream>>>(ATT, WoT, OUT, MTOT, HID, HID);
}

// Round 2
// 644.477 us; speedup vs baseline: 1.1680x; 1.1680x over previous
//
#include <hip/hip_runtime.h>
#include <stdint.h>

#define DEVINL __device__ __forceinline__

typedef __attribute__((ext_vector_type(8))) __bf16 bf16x8;
typedef __attribute__((ext_vector_type(4))) float f32x4;

static constexpr int HID  = 2048;
static constexpr int NQ   = 6144;   // 3*HID
static constexpr int SEQ  = 2048;
static constexpr int NB   = 4;
static constexpr int MTOT = NB * SEQ;  // 8192

// round-to-nearest-even f32 -> bf16
DEVINL unsigned short f2bf(float f) {
  union { float f; uint32_t u; } x; x.f = f;
  uint32_t r = x.u + 0x7fffu + ((x.u >> 16) & 1u);
  return (unsigned short)(r >> 16);
}

typedef const __attribute__((address_space(1))) void gvoid_t;
typedef __attribute__((address_space(3))) void svoid_t;

// async global->LDS, 16B per lane; LDS dest = wave-uniform base + lane*16
DEVINL void gload_lds16(const void* g, void* s) {
  __builtin_amdgcn_global_load_lds((gvoid_t*)(uintptr_t)g,
                                   (svoid_t*)(uint32_t)(uintptr_t)s,
                                   16, 0, 0);
}

// ---------------- conversion kernels ----------------

__global__ void k_cvt(const float* __restrict__ in, unsigned short* __restrict__ out, int n4) {
  int i = blockIdx.x * blockDim.x + threadIdx.x;
  if (i >= n4) return;
  float4 v = ((const float4*)in)[i];
  ushort4 o;
  o.x = f2bf(v.x); o.y = f2bf(v.y); o.z = f2bf(v.z); o.w = f2bf(v.w);
  ((ushort4*)out)[i] = o;
}

// out[c][r] = bf16(in[r][c]); in is R x C
__global__ void k_transpose_cvt(const float* __restrict__ in, unsigned short* __restrict__ out,
                                int R, int C) {
  __shared__ float tile[32][33];
  int c0 = blockIdx.x * 32, r0 = blockIdx.y * 32;
  int tx = threadIdx.x & 31, ty = threadIdx.x >> 5;  // 32 x 8
  #pragma unroll
  for (int i = 0; i < 32; i += 8)
    tile[ty + i][tx] = in[(size_t)(r0 + ty + i) * C + (c0 + tx)];
  __syncthreads();
  #pragma unroll
  for (int i = 0; i < 32; i += 8)
    out[(size_t)(c0 + ty + i) * R + (r0 + tx)] = f2bf(tile[tx][ty + i]);
}

// ---------------- GEMM: C[M][N] = A[M][K] * BT[N][K]^T ----------------
// 128x128 tile, BK=64, 4 waves (2x2), 16x16x32 bf16 MFMA, acc 4x4 per wave.

template <int OUT_BF16>
__global__ __launch_bounds__(256, 2) void k_gemm(const unsigned short* __restrict__ A,
                                                 const unsigned short* __restrict__ BT,
                                                 void* __restrict__ Cout,
                                                 int M, int N, int K) {
  __shared__ unsigned short As[128 * 64];
  __shared__ unsigned short Bs[128 * 64];
  const int tid = threadIdx.x;
  const int w = tid >> 6, l = tid & 63;
  const int lane16 = l & 15, lgrp = l >> 4;
  const int bn = blockIdx.x, bm = blockIdx.y;
  const int wr = w >> 1, wc = w & 1;
  const int srow = l >> 3;          // 0..7 within chunk
  const int sk = (l & 7) * 8;       // k-offset (elements)

  f32x4 acc[4][4] = {};

  for (int k0 = 0; k0 < K; k0 += 64) {
    #pragma unroll
    for (int i = 0; i < 4; ++i) {
      const int chunk = i * 4 + w;              // 0..15, wave-uniform
      const int row = chunk * 8 + srow;         // 0..127
      gload_lds16(A  + (size_t)(bm * 128 + row) * K + k0 + sk, As + chunk * 512);
      gload_lds16(BT + (size_t)(bn * 128 + row) * K + k0 + sk, Bs + chunk * 512);
    }
    __syncthreads();
    #pragma unroll
    for (int kk = 0; kk < 2; ++kk) {
      bf16x8 af[4], bfr[4];
      #pragma unroll
      for (int m = 0; m < 4; ++m)
        af[m] = *(const bf16x8*)(As + (wr * 64 + m * 16 + lane16) * 64 + kk * 32 + lgrp * 8);
      #pragma unroll
      for (int n = 0; n < 4; ++n)
        bfr[n] = *(const bf16x8*)(Bs + (wc * 64 + n * 16 + lane16) * 64 + kk * 32 + lgrp * 8);
      #pragma unroll
      for (int m = 0; m < 4; ++m)
        #pragma unroll
        for (int n = 0; n < 4; ++n)
          acc[m][n] = __builtin_amdgcn_mfma_f32_16x16x32_bf16(af[m], bfr[n], acc[m][n], 0, 0, 0);
    }
    __syncthreads();
  }

  const int row0 = bm * 128 + wr * 64;
  const int col0 = bn * 128 + wc * 64;
  #pragma unroll
  for (int m = 0; m < 4; ++m) {
    #pragma unroll
    for (int n = 0; n < 4; ++n) {
      const int col = col0 + n * 16 + lane16;
      #pragma unroll
      for (int r = 0; r < 4; ++r) {
        const int row = row0 + m * 16 + lgrp * 4 + r;
        if (OUT_BF16)
          ((unsigned short*)Cout)[(size_t)row * N + col] = f2bf(acc[m][n][r]);
        else
          ((float*)Cout)[(size_t)row * N + col] = acc[m][n][r];
      }
    }
  }
}

// ---------------- build V^T per head ----------------
// Vt[(head*128 + d)*2048 + t] = QKV[b*2048 + h*128 + (t>>4)][(t&15)*384 + 256 + d]
__global__ void k_build_vt(const unsigned short* __restrict__ QKV, unsigned short* __restrict__ Vt) {
  const int head = blockIdx.y;       // 0..63
  const int s_rel = blockIdx.x;      // 0..127
  const int b = head >> 4, h = head & 15;
  const int d = threadIdx.x;         // 0..127
  const unsigned short* src = QKV + (size_t)(b * SEQ + h * 128 + s_rel) * NQ + 256 + d;
  unsigned short vals[16];
  #pragma unroll
  for (int c1 = 0; c1 < 16; ++c1) vals[c1] = src[c1 * 384];
  unsigned short* dst = Vt + ((size_t)head * 128 + d) * SEQ + s_rel * 16;
  #pragma unroll
  for (int c1 = 0; c1 < 16; ++c1) dst[c1] = vals[c1];
}

// ---------------- flash attention ----------------
// grid: (qt 0..15, head 0..63), 256 threads (4 waves). Each wave: 32 q-rows.
// All three LDS tiles are XOR-swizzled: phys_col_elem = col_elem ^ ((row&7)<<3)
// (byte bits 4-6 ^= row bits 0-2). Ks/Vs are staged via global_load_lds (linear
// LDS dest), so the swizzle is applied by permuting the per-lane GLOBAL source
// address (rule #21: both-sides-or-neither); reads apply the same XOR.
__global__ __launch_bounds__(256, 2) void k_attn(const unsigned short* __restrict__ QKV,
                                                 const unsigned short* __restrict__ Vt,
                                                 unsigned short* __restrict__ ATT) {
  __shared__ unsigned short Ks[64 * 128];   // [kv][d]   (swizzled)
  __shared__ unsigned short Vs[128 * 64];   // [d][kv]   (swizzled)
  __shared__ unsigned short Ps[4 * 32 * 64];// per-wave [q][kv] (swizzled)
  const int tid = threadIdx.x, w = tid >> 6, l = tid & 63;
  const int lane16 = l & 15, lgrp = l >> 4;
  const int qt = blockIdx.x, head = blockIdx.y;
  const int b = head >> 4, h = head & 15;
  const float scale = 0.08838834764831845f;  // 1/sqrt(128)
  const int base_row = b * SEQ + h * 128;
  const int rsw = (lane16 & 7) << 3;         // read-side XOR for row=...+lane16 tiles

  // Q fragments in registers: rows w*32 + m*16 + lane16, d = kb*32 + lgrp*8 ..+8
  bf16x8 qf[2][4];
  #pragma unroll
  for (int m = 0; m < 2; ++m) {
    const int rl = w * 32 + m * 16 + lane16;   // 0..127 local q row
    const unsigned short* qrow =
        QKV + (size_t)(base_row + qt * 8 + (rl >> 4)) * NQ + (rl & 15) * 384;
    #pragma unroll
    for (int kb = 0; kb < 4; ++kb)
      qf[m][kb] = *(const bf16x8*)(qrow + kb * 32 + lgrp * 8);
  }

  f32x4 oacc[2][8] = {};
  float mrun[2][4], lrun[2][4];
  #pragma unroll
  for (int m = 0; m < 2; ++m)
    #pragma unroll
    for (int r = 0; r < 4; ++r) { mrun[m][r] = -1e30f; lrun[m][r] = 0.f; }

  for (int kv0 = 0; kv0 < SEQ; kv0 += 64) {
    // stage K tile [64][128] swizzled: lane's phys slot (row=chunk*4+lgrp,
    // col=lane16*8) receives logical col (lane16 ^ (row&7))*8
    #pragma unroll
    for (int i = 0; i < 4; ++i) {
      const int chunk = i * 4 + w;
      const int r = chunk * 4 + lgrp;          // kv row 0..63
      const int colsw = (lane16 ^ (r & 7)) * 8;
      const unsigned short* gk =
          QKV + (size_t)(base_row + (kv0 >> 4) + (r >> 4)) * NQ + (r & 15) * 384 + 128 + colsw;
      gload_lds16(gk, Ks + chunk * 512);
    }
    // stage V^T tile [128][64] swizzled: phys (row=chunk*8+(l>>3), col=(l&7)*8)
    // receives logical col ((l&7) ^ (row&7))*8
    #pragma unroll
    for (int i = 0; i < 4; ++i) {
      const int chunk = i * 4 + w;
      const int dr = chunk * 8 + (l >> 3);
      const int colsw = ((l & 7) ^ (l >> 3)) * 8;
      const unsigned short* gv = Vt + ((size_t)head * 128 + dr) * SEQ + kv0 + colsw;
      gload_lds16(gv, Vs + chunk * 512);
    }
    __syncthreads();

    // S = Q K^T   (2 m-frags x 4 n-frags of 16x16, contraction over d=128)
    f32x4 sacc[2][4] = {};
    __builtin_amdgcn_s_setprio(1);
    #pragma unroll
    for (int kb = 0; kb < 4; ++kb) {
      bf16x8 kf[4];
      #pragma unroll
      for (int n = 0; n < 4; ++n)
        kf[n] = *(const bf16x8*)(Ks + (n * 16 + lane16) * 128 + ((kb * 32 + lgrp * 8) ^ rsw));
      #pragma unroll
      for (int m = 0; m < 2; ++m)
        #pragma unroll
        for (int n = 0; n < 4; ++n)
          sacc[m][n] = __builtin_amdgcn_mfma_f32_16x16x32_bf16(qf[m][kb], kf[n], sacc[m][n], 0, 0, 0);
    }
    __builtin_amdgcn_s_setprio(0);

    // online softmax; write P (bf16) to per-wave swizzled LDS
    unsigned short* Pw = Ps + w * 2048;
    #pragma unroll
    for (int m = 0; m < 2; ++m) {
      #pragma unroll
      for (int r = 0; r < 4; ++r) {
        float mx = fmaxf(fmaxf(sacc[m][0][r], sacc[m][1][r]),
                         fmaxf(sacc[m][2][r], sacc[m][3][r]));
        #pragma unroll
        for (int off = 1; off < 16; off <<= 1) mx = fmaxf(mx, __shfl_xor(mx, off));
        const float mnew = fmaxf(mrun[m][r], mx);
        const float corr = __expf((mrun[m][r] - mnew) * scale);
        const int prow = m * 16 + lgrp * 4 + r;
        const int psw = (prow & 7) << 3;
        float ls = 0.f;
        #pragma unroll
        for (int n = 0; n < 4; ++n) {
          float p = __expf((sacc[m][n][r] - mnew) * scale);
          ls += p;
          Pw[prow * 64 + ((n * 16 + lane16) ^ psw)] = f2bf(p);
        }
        #pragma unroll
        for (int off = 1; off < 16; off <<= 1) ls += __shfl_xor(ls, off);
        lrun[m][r] = lrun[m][r] * corr + ls;
        mrun[m][r] = mnew;
        #pragma unroll
        for (int nd = 0; nd < 8; ++nd) oacc[m][nd][r] *= corr;
      }
    }
    __syncthreads();  // P visible / safety

    // O += P V  (contraction over kv=64)
    __builtin_amdgcn_s_setprio(1);
    #pragma unroll
    for (int kb = 0; kb < 2; ++kb) {
      bf16x8 pf[2];
      #pragma unroll
      for (int m = 0; m < 2; ++m)
        pf[m] = *(const bf16x8*)(Pw + (m * 16 + lane16) * 64 + ((kb * 32 + lgrp * 8) ^ rsw));
      #pragma unroll
      for (int nd = 0; nd < 8; ++nd) {
        bf16x8 vf = *(const bf16x8*)(Vs + (nd * 16 + lane16) * 64 + ((kb * 32 + lgrp * 8) ^ rsw));
        #pragma unroll
        for (int m = 0; m < 2; ++m)
          oacc[m][nd] = __builtin_amdgcn_mfma_f32_16x16x32_bf16(pf[m], vf, oacc[m][nd], 0, 0, 0);
      }
    }
    __builtin_amdgcn_s_setprio(0);
    __syncthreads();  // before re-staging K/Vs
  }

  // epilogue: O /= l, scatter to ATT[b*2048 + h*128 + (t>>4)][(t&15)*128 + d]
  #pragma unroll
  for (int m = 0; m < 2; ++m) {
    #pragma unroll
    for (int r = 0; r < 4; ++r) {
      const float inv = 1.0f / lrun[m][r];
      const int rl = w * 32 + m * 16 + lgrp * 4 + r;  // local q row
      unsigned short* orow =
          ATT + (size_t)(base_row + qt * 8 + (rl >> 4)) * HID + (rl & 15) * 128;
      #pragma unroll
      for (int nd = 0; nd < 8; ++nd)
        orow[nd * 16 + lane16] = f2bf(oacc[m][nd][r] * inv);
    }
  }
}

// ---------------- launcher ----------------

extern "C" void kernel_launch(void* const* d_in, const int* in_sizes, int n_in,
                              void* d_out, int out_size, void* d_ws, size_t ws_size,
                              hipStream_t stream) {
  const float* X    = (const float*)d_in[0];  // (4,2048,2048)
  const float* Wqkv = (const float*)d_in[1];  // (2048,6144)
  const float* Wo   = (const float*)d_in[2];  // (2048,2048)
  float* OUT = (float*)d_out;

  char* ws = (char*)d_ws;
  constexpr size_t SZ_QKV   = (size_t)MTOT * NQ * 2;    // 100663296
  constexpr size_t SZ_XBF   = (size_t)MTOT * HID * 2;   //  33554432
  constexpr size_t SZ_WQKVT = (size_t)NQ * HID * 2;     //  25165824
  constexpr size_t SZ_WOT   = (size_t)HID * HID * 2;    //   8388608
  constexpr size_t SZ_VT    = (size_t)64 * 128 * SEQ * 2; // 33554432
  unsigned short* QKV   = (unsigned short*)(ws);
  unsigned short* Xbf   = (unsigned short*)(ws + SZ_QKV);
  unsigned short* WqkvT = (unsigned short*)(ws + SZ_QKV + SZ_XBF);
  unsigned short* WoT   = (unsigned short*)(ws + SZ_QKV + SZ_XBF + SZ_WQKVT);
  unsigned short* Vt    = (unsigned short*)(ws + SZ_QKV + SZ_XBF + SZ_WQKVT + SZ_WOT);
  unsigned short* ATT   = (unsigned short*)(ws + SZ_QKV + SZ_XBF + SZ_WQKVT + SZ_WOT + SZ_VT);

  // 1) convert / transpose weights+activations to bf16
  k_cvt<<<(MTOT * HID / 4 + 255) / 256, 256, 0, stream>>>(X, Xbf, MTOT * HID / 4);
  k_transpose_cvt<<<dim3(NQ / 32, HID / 32), 256, 0, stream>>>(Wqkv, WqkvT, HID, NQ);
  k_transpose_cvt<<<dim3(HID / 32, HID / 32), 256, 0, stream>>>(Wo, WoT, HID, HID);
  // 2) QKV projection
  k_gemm<1><<<dim3(NQ / 128, MTOT / 128), 256, 0, stream>>>(Xbf, WqkvT, QKV, MTOT, NQ, HID);
  // 3) gather V^T per head
  k_build_vt<<<dim3(128, 64), 128, 0, stream>>>(QKV, Vt);
  // 4) flash attention
  k_attn<<<dim3(16, 64), 256, 0, stream>>>(QKV, Vt, ATT);
  // 5) output projection
  k_gemm<0><<<dim3(HID / 128, MTOT / 128), 256, 0, stream>>>(ATT, WoT, OUT, MTOT, HID, HID);
}

// Round 3
// 550.592 us; speedup vs baseline: 1.3672x; 1.1705x over previous
//
#include <hip/hip_runtime.h>
#include <stdint.h>

#define DEVINL __device__ __forceinline__

typedef __attribute__((ext_vector_type(8))) __bf16 bf16x8;
typedef __attribute__((ext_vector_type(4))) float f32x4;
typedef __attribute__((ext_vector_type(16))) float f32x16;

static constexpr int HID  = 2048;
static constexpr int NQ   = 6144;   // 3*HID
static constexpr int SEQ  = 2048;
static constexpr int NB   = 4;
static constexpr int MTOT = NB * SEQ;  // 8192

// round-to-nearest-even f32 -> bf16
DEVINL unsigned short f2bf(float f) {
  union { float f; uint32_t u; } x; x.f = f;
  uint32_t r = x.u + 0x7fffu + ((x.u >> 16) & 1u);
  return (unsigned short)(r >> 16);
}

typedef const __attribute__((address_space(1))) void gvoid_t;
typedef __attribute__((address_space(3))) void svoid_t;

// async global->LDS, 16B per lane; LDS dest = wave-uniform base + lane*16
DEVINL void gload_lds16(const void* g, void* s) {
  __builtin_amdgcn_global_load_lds((gvoid_t*)(uintptr_t)g,
                                   (svoid_t*)(uint32_t)(uintptr_t)s,
                                   16, 0, 0);
}

// ---------------- conversion kernels ----------------

__global__ void k_cvt(const float* __restrict__ in, unsigned short* __restrict__ out, int n4) {
  int i = blockIdx.x * blockDim.x + threadIdx.x;
  if (i >= n4) return;
  float4 v = ((const float4*)in)[i];
  ushort4 o;
  o.x = f2bf(v.x); o.y = f2bf(v.y); o.z = f2bf(v.z); o.w = f2bf(v.w);
  ((ushort4*)out)[i] = o;
}

// out[c][r] = bf16(in[r][c]); in is R x C
__global__ void k_transpose_cvt(const float* __restrict__ in, unsigned short* __restrict__ out,
                                int R, int C) {
  __shared__ float tile[32][33];
  int c0 = blockIdx.x * 32, r0 = blockIdx.y * 32;
  int tx = threadIdx.x & 31, ty = threadIdx.x >> 5;  // 32 x 8
  #pragma unroll
  for (int i = 0; i < 32; i += 8)
    tile[ty + i][tx] = in[(size_t)(r0 + ty + i) * C + (c0 + tx)];
  __syncthreads();
  #pragma unroll
  for (int i = 0; i < 32; i += 8)
    out[(size_t)(c0 + ty + i) * R + (r0 + tx)] = f2bf(tile[tx][ty + i]);
}

// ---------------- GEMM: C[M][N] = A[M][K] * BT[N][K]^T ----------------
// 128x128 tile, BK=64, 4 waves (2x2), 16x16x32 bf16 MFMA, acc 4x4 per wave.

template <int OUT_BF16>
__global__ __launch_bounds__(256, 2) void k_gemm(const unsigned short* __restrict__ A,
                                                 const unsigned short* __restrict__ BT,
                                                 void* __restrict__ Cout,
                                                 int M, int N, int K) {
  __shared__ unsigned short As[128 * 64];
  __shared__ unsigned short Bs[128 * 64];
  const int tid = threadIdx.x;
  const int w = tid >> 6, l = tid & 63;
  const int lane16 = l & 15, lgrp = l >> 4;
  const int bn = blockIdx.x, bm = blockIdx.y;
  const int wr = w >> 1, wc = w & 1;
  const int srow = l >> 3;          // 0..7 within chunk
  const int sk = (l & 7) * 8;       // k-offset (elements)

  f32x4 acc[4][4] = {};

  for (int k0 = 0; k0 < K; k0 += 64) {
    #pragma unroll
    for (int i = 0; i < 4; ++i) {
      const int chunk = i * 4 + w;              // 0..15, wave-uniform
      const int row = chunk * 8 + srow;         // 0..127
      gload_lds16(A  + (size_t)(bm * 128 + row) * K + k0 + sk, As + chunk * 512);
      gload_lds16(BT + (size_t)(bn * 128 + row) * K + k0 + sk, Bs + chunk * 512);
    }
    __syncthreads();
    #pragma unroll
    for (int kk = 0; kk < 2; ++kk) {
      bf16x8 af[4], bfr[4];
      #pragma unroll
      for (int m = 0; m < 4; ++m)
        af[m] = *(const bf16x8*)(As + (wr * 64 + m * 16 + lane16) * 64 + kk * 32 + lgrp * 8);
      #pragma unroll
      for (int n = 0; n < 4; ++n)
        bfr[n] = *(const bf16x8*)(Bs + (wc * 64 + n * 16 + lane16) * 64 + kk * 32 + lgrp * 8);
      #pragma unroll
      for (int m = 0; m < 4; ++m)
        #pragma unroll
        for (int n = 0; n < 4; ++n)
          acc[m][n] = __builtin_amdgcn_mfma_f32_16x16x32_bf16(af[m], bfr[n], acc[m][n], 0, 0, 0);
    }
    __syncthreads();
  }

  const int row0 = bm * 128 + wr * 64;
  const int col0 = bn * 128 + wc * 64;
  #pragma unroll
  for (int m = 0; m < 4; ++m) {
    #pragma unroll
    for (int n = 0; n < 4; ++n) {
      const int col = col0 + n * 16 + lane16;
      #pragma unroll
      for (int r = 0; r < 4; ++r) {
        const int row = row0 + m * 16 + lgrp * 4 + r;
        if (OUT_BF16)
          ((unsigned short*)Cout)[(size_t)row * N + col] = f2bf(acc[m][n][r]);
        else
          ((float*)Cout)[(size_t)row * N + col] = acc[m][n][r];
      }
    }
  }
}

// ---------------- build V^T per head ----------------
// Vt[(head*128 + d)*2048 + t] = QKV[b*2048 + h*128 + (t>>4)][(t&15)*384 + 256 + d]
__global__ void k_build_vt(const unsigned short* __restrict__ QKV, unsigned short* __restrict__ Vt) {
  const int head = blockIdx.y;       // 0..63
  const int s_rel = blockIdx.x;      // 0..127
  const int b = head >> 4, h = head & 15;
  const int d = threadIdx.x;         // 0..127
  const unsigned short* src = QKV + (size_t)(b * SEQ + h * 128 + s_rel) * NQ + 256 + d;
  unsigned short vals[16];
  #pragma unroll
  for (int c1 = 0; c1 < 16; ++c1) vals[c1] = src[c1 * 384];
  unsigned short* dst = Vt + ((size_t)head * 128 + d) * SEQ + s_rel * 16;
  #pragma unroll
  for (int c1 = 0; c1 < 16; ++c1) dst[c1] = vals[c1];
}

// ---------------- flash attention (swapped-QK, in-register softmax) --------
// grid: (qt 0..15, head 0..63), 256 threads = 4 waves; each wave owns 32 q.
// Per kv-tile (KVBLK=64), per wave:
//   S^T[kv][q] = mfma_32x32x16(K-frag, Q-frag) x16   (lane: q=l&31, 16 kv vals)
//   in-register online softmax (tree reduce + one shfl_xor(32)); defer-max T13
//   P^T built in-register: 16 v_cvt_pk_bf16_f32 + 8 v_permlane32_swap_b32
//   O^T[d][q] += mfma_32x32x16(V^T-frag, P^T-frag) x16
// K/V double-buffered in LDS (64 KiB), staged by global_load_lds with
// inverse-swizzled global source (rule #21); prefetch issued before compute.
__global__ __launch_bounds__(256, 2) void k_attn(const unsigned short* __restrict__ QKV,
                                                 const unsigned short* __restrict__ Vt,
                                                 unsigned short* __restrict__ ATT) {
  __shared__ unsigned short Ks[2][64 * 128];   // [kv][d]  4-bit XOR swizzle
  __shared__ unsigned short Vs[2][128 * 64];   // [d][kv]  3-bit XOR swizzle
  const int tid = threadIdx.x, w = tid >> 6, l = tid & 63;
  const int l32 = l & 31, hi = l >> 5;
  const int qt = blockIdx.x, head = blockIdx.y;
  const int b = head >> 4, h = head & 15;
  const float scale = 0.08838834764831845f;   // 1/sqrt(128)
  const float THR = 8.0f / 0.08838834764831845f;  // defer-max threshold (raw units)
  const int base_row = b * SEQ + h * 128;

  // Q fragments: this lane serves q-column (l&31) of the wave's 32-q block.
  // B-frag k-slot mapping f(hi,e) = hi*8+e over d; consistent with K A-frags.
  const int s = qt * 128 + w * 32 + l32;      // global seq position of my q
  bf16x8 qf[8];
  {
    const unsigned short* qrow = QKV + (size_t)(base_row + (s >> 4)) * NQ + (s & 15) * 384;
    #pragma unroll
    for (int dsl = 0; dsl < 8; ++dsl)
      qf[dsl] = *(const bf16x8*)(qrow + dsl * 16 + hi * 8);
  }

  f32x16 oacc[4] = {};   // O^T d-frags: row=d-local (C layout), col=q=l&31
  float mrun = -1e30f, lrun = 0.0f;

  #define STAGE_KV(bb, kv0)                                                              \
    {                                                                                    \
      _Pragma("unroll")                                                                  \
      for (int i = 0; i < 4; ++i) {                                                      \
        const int chunk = i * 4 + w;                                                     \
        const int r = chunk * 4 + (l >> 4);                                              \
        const int colsw = ((l & 15) ^ (r & 15)) * 8;                                     \
        gload_lds16(QKV + (size_t)(base_row + ((kv0) >> 4) + (r >> 4)) * NQ              \
                        + (r & 15) * 384 + 128 + colsw,                                  \
                    &Ks[bb][chunk * 512]);                                               \
      }                                                                                  \
      _Pragma("unroll")                                                                  \
      for (int i = 0; i < 4; ++i) {                                                      \
        const int chunk = i * 4 + w;                                                     \
        const int dr = chunk * 8 + (l >> 3);                                             \
        const int colsw = ((l & 7) ^ (dr & 7)) * 8;                                      \
        gload_lds16(Vt + ((size_t)head * 128 + dr) * SEQ + (kv0) + colsw,                \
                    &Vs[bb][chunk * 512]);                                               \
      }                                                                                  \
    }

  STAGE_KV(0, 0);
  __syncthreads();

  int buf = 0;
  for (int kv0 = 0; kv0 < SEQ; kv0 += 64) {
    if (kv0 + 64 < SEQ) STAGE_KV(buf ^ 1, kv0 + 64);   // prefetch overlaps compute

    // ---- S^T = K * Q^T ----
    f32x16 sacc[2] = {};
    __builtin_amdgcn_s_setprio(1);
    #pragma unroll
    for (int kvf = 0; kvf < 2; ++kvf) {
      const int row = kvf * 32 + l32;
      const unsigned short* kbase = &Ks[buf][row * 128];
      const int rs = (row & 15) << 3;
      #pragma unroll
      for (int dsl = 0; dsl < 8; ++dsl) {
        bf16x8 kf = *(const bf16x8*)(kbase + ((dsl * 16 + hi * 8) ^ rs));
        sacc[kvf] = __builtin_amdgcn_mfma_f32_32x32x16_bf16(kf, qf[dsl], sacc[kvf], 0, 0, 0);
      }
    }
    __builtin_amdgcn_s_setprio(0);

    // ---- online softmax, fully in-register ----
    // tile max (tree): lane holds 32 of 64 kv for its q; partner has the rest
    float mx[16];
    #pragma unroll
    for (int r = 0; r < 16; ++r) mx[r] = fmaxf(sacc[0][r], sacc[1][r]);
    #pragma unroll
    for (int st = 8; st >= 1; st >>= 1)
      #pragma unroll
      for (int r = 0; r < st; ++r) mx[r] = fmaxf(mx[r], mx[r + st]);
    float pmax = fmaxf(mx[0], __shfl_xor(mx[0], 32));

    if (!__all(pmax - mrun <= THR)) {      // T13 defer-max: rescale rarely
      const float mnew = fmaxf(mrun, pmax);
      const float corr = __expf((mrun - mnew) * scale);
      #pragma unroll
      for (int df = 0; df < 4; ++df)
        #pragma unroll
        for (int r = 0; r < 16; ++r) oacc[df][r] *= corr;
      lrun *= corr;
      mrun = mnew;
    }

    float ps[16];
    #pragma unroll
    for (int r = 0; r < 16; ++r) {
      const float p0 = __expf((sacc[0][r] - mrun) * scale);
      const float p1 = __expf((sacc[1][r] - mrun) * scale);
      sacc[0][r] = p0; sacc[1][r] = p1;
      ps[r] = p0 + p1;
    }
    #pragma unroll
    for (int st = 8; st >= 1; st >>= 1)
      #pragma unroll
      for (int r = 0; r < st; ++r) ps[r] += ps[r + st];
    lrun += ps[0] + __shfl_xor(ps[0], 32);

    // ---- P^T -> bf16 B-fragments: cvt_pk + permlane32_swap (T12) ----
    bf16x8 pf[4];
    #pragma unroll
    for (int f = 0; f < 2; ++f) {
      unsigned int c0, c1, c2, c3, c4, c5, c6, c7;
      asm("v_cvt_pk_bf16_f32 %0, %1, %2" : "=v"(c0) : "v"(sacc[f][0]),  "v"(sacc[f][1]));
      asm("v_cvt_pk_bf16_f32 %0, %1, %2" : "=v"(c1) : "v"(sacc[f][2]),  "v"(sacc[f][3]));
      asm("v_cvt_pk_bf16_f32 %0, %1, %2" : "=v"(c2) : "v"(sacc[f][4]),  "v"(sacc[f][5]));
      asm("v_cvt_pk_bf16_f32 %0, %1, %2" : "=v"(c3) : "v"(sacc[f][6]),  "v"(sacc[f][7]));
      asm("v_cvt_pk_bf16_f32 %0, %1, %2" : "=v"(c4) : "v"(sacc[f][8]),  "v"(sacc[f][9]));
      asm("v_cvt_pk_bf16_f32 %0, %1, %2" : "=v"(c5) : "v"(sacc[f][10]), "v"(sacc[f][11]));
      asm("v_cvt_pk_bf16_f32 %0, %1, %2" : "=v"(c6) : "v"(sacc[f][12]), "v"(sacc[f][13]));
      asm("v_cvt_pk_bf16_f32 %0, %1, %2" : "=v"(c7) : "v"(sacc[f][14]), "v"(sacc[f][15]));
      asm("v_permlane32_swap_b32 %0, %1" : "+v"(c0), "+v"(c2));
      asm("v_permlane32_swap_b32 %0, %1" : "+v"(c1), "+v"(c3));
      asm("v_permlane32_swap_b32 %0, %1" : "+v"(c4), "+v"(c6));
      asm("v_permlane32_swap_b32 %0, %1" : "+v"(c5), "+v"(c7));
      union { unsigned int u[4]; bf16x8 v; } u0, u1;
      u0.u[0] = c0; u0.u[1] = c1; u0.u[2] = c2; u0.u[3] = c3;
      u1.u[0] = c4; u1.u[1] = c5; u1.u[2] = c6; u1.u[3] = c7;
      pf[2 * f] = u0.v; pf[2 * f + 1] = u1.v;
    }

    // ---- O^T += V^T * P^T ----
    __builtin_amdgcn_s_setprio(1);
    #pragma unroll
    for (int ks = 0; ks < 4; ++ks) {
      #pragma unroll
      for (int df = 0; df < 4; ++df) {
        const int row = df * 32 + l32;
        bf16x8 vf = *(const bf16x8*)(&Vs[buf][row * 64 + (((ks * 16 + hi * 8) ^ ((row & 7) << 3)))]);
        oacc[df] = __builtin_amdgcn_mfma_f32_32x32x16_bf16(vf, pf[ks], oacc[df], 0, 0, 0);
      }
    }
    __builtin_amdgcn_s_setprio(0);

    __syncthreads();   // all reads of buf done; prefetch of buf^1 drained
    buf ^= 1;
  }

  // epilogue: O^T/l -> ATT[b*2048+h*128+(s>>4)][(s&15)*128 + d]
  const float inv = 1.0f / lrun;
  unsigned short* orow = ATT + (size_t)(base_row + (s >> 4)) * HID + (s & 15) * 128;
  #pragma unroll
  for (int df = 0; df < 4; ++df) {
    #pragma unroll
    for (int k = 0; k < 4; ++k) {   // d = df*32 + 8k + 4hi + (0..3)
      ushort4 o;
      o.x = f2bf(oacc[df][4 * k + 0] * inv);
      o.y = f2bf(oacc[df][4 * k + 1] * inv);
      o.z = f2bf(oacc[df][4 * k + 2] * inv);
      o.w = f2bf(oacc[df][4 * k + 3] * inv);
      *(ushort4*)(orow + df * 32 + 8 * k + 4 * hi) = o;
    }
  }
}

// ---------------- launcher ----------------

extern "C" void kernel_launch(void* const* d_in, const int* in_sizes, int n_in,
                              void* d_out, int out_size, void* d_ws, size_t ws_size,
                              hipStream_t stream) {
  const float* X    = (const float*)d_in[0];  // (4,2048,2048)
  const float* Wqkv = (const float*)d_in[1];  // (2048,6144)
  const float* Wo   = (const float*)d_in[2];  // (2048,2048)
  float* OUT = (float*)d_out;

  char* ws = (char*)d_ws;
  constexpr size_t SZ_QKV   = (size_t)MTOT * NQ * 2;    // 100663296
  constexpr size_t SZ_XBF   = (size_t)MTOT * HID * 2;   //  33554432
  constexpr size_t SZ_WQKVT = (size_t)NQ * HID * 2;     //  25165824
  constexpr size_t SZ_WOT   = (size_t)HID * HID * 2;    //   8388608
  constexpr size_t SZ_VT    = (size_t)64 * 128 * SEQ * 2; // 33554432
  unsigned short* QKV   = (unsigned short*)(ws);
  unsigned short* Xbf   = (unsigned short*)(ws + SZ_QKV);
  unsigned short* WqkvT = (unsigned short*)(ws + SZ_QKV + SZ_XBF);
  unsigned short* WoT   = (unsigned short*)(ws + SZ_QKV + SZ_XBF + SZ_WQKVT);
  unsigned short* Vt    = (unsigned short*)(ws + SZ_QKV + SZ_XBF + SZ_WQKVT + SZ_WOT);
  unsigned short* ATT   = (unsigned short*)(ws + SZ_QKV + SZ_XBF + SZ_WQKVT + SZ_WOT + SZ_VT);

  // 1) convert / transpose weights+activations to bf16
  k_cvt<<<(MTOT * HID / 4 + 255) / 256, 256, 0, stream>>>(X, Xbf, MTOT * HID / 4);
  k_transpose_cvt<<<dim3(NQ / 32, HID / 32), 256, 0, stream>>>(Wqkv, WqkvT, HID, NQ);
  k_transpose_cvt<<<dim3(HID / 32, HID / 32), 256, 0, stream>>>(Wo, WoT, HID, HID);
  // 2) QKV projection
  k_gemm<1><<<dim3(NQ / 128, MTOT / 128), 256, 0, stream>>>(Xbf, WqkvT, QKV, MTOT, NQ, HID);
  // 3) gather V^T per head
  k_build_vt<<<dim3(128, 64), 128, 0, stream>>>(QKV, Vt);
  // 4) flash attention
  k_attn<<<dim3(16, 64), 256, 0, stream>>>(QKV, Vt, ATT);
  // 5) output projection
  k_gemm<0><<<dim3(HID / 128, MTOT / 128), 256, 0, stream>>>(ATT, WoT, OUT, MTOT, HID, HID);
}